// Round 1
// baseline (76.043 us; speedup 1.0000x reference)
//
#include <hip/hip_runtime.h>

// QuantumConv2d on MI355X.
// One thread per 2x2 patch: 4 angles -> 16 diagonal phases -> 4 RX butterfly
// stages -> CNOT-ring (compile-time bit parity masks) -> 4 outputs.
//
// Patch decode (from reference _PERM): patch p = u*128+v covers
// x[b, 2v, 2u], x[b, 2v, 2u+1], x[b, 2v+1, 2u], x[b, 2v+1, 2u+1]  (q = 0..3)
// and output (after swapaxes) is out[b, v, u, q].
//
// CNOT ring as GF(2) bit map (b0..b3 LSB-first -> r0..r3):
//   r0 = b1^b2^b3, r1 = b0^b1, r2 = b0^b1^b2, r3 = b0^b1^b2^b3
// out_q selects bit (3-q) of r (STATES is MSB-first):
//   out0: b0^b1^b2^b3,  out1: b0^b1^b2,  out2: b0^b1,  out3: b1^b2^b3

__global__ __launch_bounds__(256) void qconv2d_kernel(
    const float* __restrict__ x,   // [64, 256, 256]
    const float* __restrict__ w,   // [4]
    float* __restrict__ out)       // [64, 128, 128, 4]
{
    const int idx = blockIdx.x * 256 + threadIdx.x;   // b*16384 + v*128 + u
    const int u = idx & 127;
    const int v = (idx >> 7) & 127;
    const int b = idx >> 14;

    // ---- load the 2x2 patch (two coalesced float2 loads) ----
    const float* base = x + ((size_t)b << 16) + ((size_t)(v << 1) << 8) + (u << 1);
    const float2 r0 = *(const float2*)(base);
    const float2 r1 = *(const float2*)(base + 256);
    const float x0 = r0.x, x1 = r0.y, x2 = r1.x, x3 = r1.y;

    // ---- weight-dependent RX gate coefficients (uniform scalars) ----
    float cw[4], sw[4];
#pragma unroll
    for (int q = 0; q < 4; ++q) {
        __sincosf(0.5f * w[q], &sw[q], &cw[q]);
    }

    // ---- diagonal RZ+RZZ phases: d_k = exp(-i*phi_k) ----
    const float s2 = x0*x0 + x1*x1 + x2*x2 + x3*x3;
    float yr[16], yi[16];
#pragma unroll
    for (int k = 0; k < 16; ++k) {
        const float t = ((k & 1) ? x0 : -x0) + ((k & 2) ? x1 : -x1)
                      + ((k & 4) ? x2 : -x2) + ((k & 8) ? x3 : -x3);
        // phi = 0.5*t + 0.25*t^2 - 0.25*s2
        const float phi = fmaf(t, fmaf(0.25f, t, 0.5f), -0.25f * s2);
        float sn, cs;
        __sincosf(phi, &sn, &cs);
        yr[k] = cs;
        yi[k] = -sn;
    }

    // ---- apply U = RX(w3) (x) RX(w2) (x) RX(w1) (x) RX(w0): 4 butterfly stages ----
    // RX pair: y0' = c*y0 + (-i s)*y1 ; y1' = (-i s)*y0 + c*y1
#pragma unroll
    for (int q = 0; q < 4; ++q) {
        const float c = cw[q], s = sw[q];
#pragma unroll
        for (int k0 = 0; k0 < 16; ++k0) {
            if (k0 & (1 << q)) continue;
            const int k1 = k0 | (1 << q);
            const float ar = yr[k0], ai = yi[k0];
            const float br = yr[k1], bi = yi[k1];
            yr[k0] = fmaf(c, ar,  s * bi);
            yi[k0] = fmaf(c, ai, -s * br);
            yr[k1] = fmaf(c, br,  s * ai);
            yi[k1] = fmaf(c, bi, -s * ar);
        }
    }

    // ---- probabilities + CNOT-ring parity masks -> 4 outputs ----
    float o0 = 0.f, o1 = 0.f, o2 = 0.f, o3 = 0.f;
#pragma unroll
    for (int j = 0; j < 16; ++j) {
        const float p = fmaf(yr[j], yr[j], yi[j] * yi[j]);
        const int b0 = j & 1, b1 = (j >> 1) & 1, b2 = (j >> 2) & 1, b3 = (j >> 3) & 1;
        if (b0 ^ b1 ^ b2 ^ b3) o0 += p;
        if (b0 ^ b1 ^ b2)      o1 += p;
        if (b0 ^ b1)           o2 += p;
        if (b1 ^ b2 ^ b3)      o3 += p;
    }

    // state scale 0.25 -> prob scale 0.0625
    float4 res;
    res.x = 0.0625f * o0;
    res.y = 0.0625f * o1;
    res.z = 0.0625f * o2;
    res.w = 0.0625f * o3;
    *(float4*)(out + ((size_t)idx << 2)) = res;
}

extern "C" void kernel_launch(void* const* d_in, const int* in_sizes, int n_in,
                              void* d_out, int out_size, void* d_ws, size_t ws_size,
                              hipStream_t stream) {
    const float* x = (const float*)d_in[0];   // [64,256,256] fp32
    const float* w = (const float*)d_in[1];   // [2,2] fp32
    float* out = (float*)d_out;               // [64,128,128,4] fp32

    const int total = 64 * 128 * 128;         // 1,048,576 threads (one per patch)
    qconv2d_kernel<<<dim3(total / 256), dim3(256), 0, stream>>>(x, w, out);
}

// Round 2
// 75.509 us; speedup vs baseline: 1.0071x; 1.0071x over previous
//
#include <hip/hip_runtime.h>

// QuantumConv2d on MI355X — one thread per 2x2 patch.
// R1: native v_sin_f32/v_cos_f32 (args in REVOLUTIONS, |phi| < 32 rev here),
//     phase computed directly in revolutions, pre-summed ±x pairs.
//
// Patch decode (from reference _PERM): patch p = u*128+v covers
//   x[b, 2v, 2u..2u+1], x[b, 2v+1, 2u..2u+1]  (q = 0..3, row-major in patch)
// and output (after swapaxes) is out[b, v, u, q].
//
// CNOT ring == GF(2) bit permutation; with STATES MSB-first the 4 outputs are
// parity-masked sums of |y_j|^2:
//   out0: b0^b1^b2^b3,  out1: b0^b1^b2,  out2: b0^b1,  out3: b1^b2^b3

#define INV2PI 0.15915494309189535f

__global__ __launch_bounds__(256) void qconv2d_kernel(
    const float* __restrict__ x,   // [64, 256, 256]
    const float* __restrict__ w,   // [4]
    float* __restrict__ out)       // [64, 128, 128, 4]
{
    const int idx = blockIdx.x * 256 + threadIdx.x;   // b*16384 + v*128 + u
    const int u = idx & 127;
    const int v = (idx >> 7) & 127;
    const int b = idx >> 14;

    // ---- load the 2x2 patch (two coalesced float2 loads) ----
    const float* base = x + ((size_t)b << 16) + ((size_t)(v << 1) << 8) + (u << 1);
    const float2 p0 = *(const float2*)(base);
    const float2 p1 = *(const float2*)(base + 256);
    const float x0 = p0.x, x1 = p0.y, x2 = p1.x, x3 = p1.y;

    // ---- RX gate coefficients from uniform weights (native sin/cos) ----
    float cw[4], sw[4];
#pragma unroll
    for (int q = 0; q < 4; ++q) {
        const float r = w[q] * (0.5f * INV2PI);
        sw[q] = __builtin_amdgcn_sinf(r);
        cw[q] = __builtin_amdgcn_cosf(r);
    }

    // ---- diagonal phases d_k = exp(-i*phi_k), phi in revolutions ----
    // t_k = sum_q s_q x_q  (s_q = +1 if bit q of k set, else -1)
    // phi_k = 0.5*t + 0.25*t^2 - 0.25*sum(x^2)   [radians]
    // rev_k = t*(cA*t + cB) + cbase              [revolutions]
    const float a0 = x0 + x1, a1 = x0 - x1;   // lo-pair sums
    const float b0 = x2 + x3, b1 = x2 - x3;   // hi-pair sums
    const float ss = x0*x0 + x1*x1 + x2*x2 + x3*x3;
    const float cA = 0.25f * INV2PI;
    const float cB = 0.5f * INV2PI;
    const float cbase = -0.25f * INV2PI * ss;

    // lo[k&3], hi[(k>>2)&3]: signed pair sums (negations are free modifiers)
    const float lo0 = -a0, lo1 = a1, lo2 = -a1, lo3 = a0;
    const float hi0 = -b0, hi1 = b1, hi2 = -b1, hi3 = b0;

    float yr[16], yi[16];
#pragma unroll
    for (int k = 0; k < 16; ++k) {
        const float lo = (k & 1) ? ((k & 2) ? lo3 : lo1) : ((k & 2) ? lo2 : lo0);
        const float hi = (k & 4) ? ((k & 8) ? hi3 : hi1) : ((k & 8) ? hi2 : hi0);
        const float t = lo + hi;
        const float rev = fmaf(t, fmaf(cA, t, cB), cbase);
        yr[k] = __builtin_amdgcn_cosf(rev);
        yi[k] = -__builtin_amdgcn_sinf(rev);
    }

    // ---- U = (x)_q RX(w_q): 4 butterfly stages over bit q ----
    // pair: y0' = c*y0 - i*s*y1 ; y1' = -i*s*y0 + c*y1
#pragma unroll
    for (int q = 0; q < 4; ++q) {
        const float c = cw[q], s = sw[q];
#pragma unroll
        for (int k0 = 0; k0 < 16; ++k0) {
            if (k0 & (1 << q)) continue;
            const int k1 = k0 | (1 << q);
            const float ar = yr[k0], ai = yi[k0];
            const float br = yr[k1], bi = yi[k1];
            yr[k0] = fmaf(c, ar,  s * bi);
            yi[k0] = fmaf(c, ai, -(s * br));
            yr[k1] = fmaf(c, br,  s * ai);
            yi[k1] = fmaf(c, bi, -(s * ar));
        }
    }

    // ---- probabilities + parity masks -> 4 outputs ----
    float o0 = 0.f, o1 = 0.f, o2 = 0.f, o3 = 0.f;
#pragma unroll
    for (int j = 0; j < 16; ++j) {
        const float p = fmaf(yr[j], yr[j], yi[j] * yi[j]);
        const int q0 = j & 1, q1 = (j >> 1) & 1, q2 = (j >> 2) & 1, q3 = (j >> 3) & 1;
        if (q0 ^ q1 ^ q2 ^ q3) o0 += p;
        if (q0 ^ q1 ^ q2)      o1 += p;
        if (q0 ^ q1)           o2 += p;
        if (q1 ^ q2 ^ q3)      o3 += p;
    }

    float4 res;
    res.x = 0.0625f * o0;   // state scale 0.25 -> prob scale 0.0625
    res.y = 0.0625f * o1;
    res.z = 0.0625f * o2;
    res.w = 0.0625f * o3;
    *(float4*)(out + ((size_t)idx << 2)) = res;
}

extern "C" void kernel_launch(void* const* d_in, const int* in_sizes, int n_in,
                              void* d_out, int out_size, void* d_ws, size_t ws_size,
                              hipStream_t stream) {
    const float* x = (const float*)d_in[0];   // [64,256,256] fp32
    const float* w = (const float*)d_in[1];   // [2,2] fp32
    float* out = (float*)d_out;               // [64,128,128,4] fp32

    const int total = 64 * 128 * 128;         // one thread per patch
    qconv2d_kernel<<<dim3(total / 256), dim3(256), 0, stream>>>(x, w, out);
}

// Round 3
// 75.201 us; speedup vs baseline: 1.0112x; 1.0041x over previous
//
#include <hip/hip_runtime.h>

// QuantumConv2d on MI355X — R2: TWO adjacent patches per thread.
// Thread t: b = t>>13, v = (t>>6)&127, up = (t&63)*2  -> patches (up,v),(up+1,v)
// Loads: float4 from rows 2v and 2v+1 at col 4*(t&63) -> both patches' angles.
// Stores: two adjacent float4 = 32B contiguous per thread, coalesced.
//
// Per patch: 16 diagonal phasors exp(-i*phi_k) with
//   phi_k = 0.25 t^2 + 0.5 t - 0.25*sum(x^2)  (radians; evaluated in
//   revolutions for native v_sin/v_cos), t = sum_q (+-)x_q  (LSB-first signs),
// then 4 RX butterfly stages (c,s from weights, shared by both patches),
// then CNOT-ring == GF(2) bit permutation -> parity-masked |y|^2 sums:
//   out0: b0^b1^b2^b3, out1: b0^b1^b2, out2: b0^b1, out3: b1^b2^b3

#define INV2PI 0.15915494309189535f

__device__ __forceinline__ void patch_eval(
    float x0, float x1, float x2, float x3,
    const float cw[4], const float sw[4], float4* res)
{
    const float a0 = x0 + x1, a1 = x0 - x1;
    const float b0 = x2 + x3, b1 = x2 - x3;
    const float ss = x0*x0 + x1*x1 + x2*x2 + x3*x3;
    const float cA = 0.25f * INV2PI;
    const float cB = 0.5f * INV2PI;
    const float cbase = -0.25f * INV2PI * ss;

    const float lo0 = -a0, lo1 = a1, lo2 = -a1, lo3 = a0;
    const float hi0 = -b0, hi1 = b1, hi2 = -b1, hi3 = b0;

    float yr[16], yi[16];
#pragma unroll
    for (int k = 0; k < 16; ++k) {
        const float lo = (k & 1) ? ((k & 2) ? lo3 : lo1) : ((k & 2) ? lo2 : lo0);
        const float hi = (k & 4) ? ((k & 8) ? hi3 : hi1) : ((k & 8) ? hi2 : hi0);
        const float t = lo + hi;
        const float rev = fmaf(t, fmaf(cA, t, cB), cbase);
        yr[k] = __builtin_amdgcn_cosf(rev);
        yi[k] = -__builtin_amdgcn_sinf(rev);
    }

#pragma unroll
    for (int q = 0; q < 4; ++q) {
        const float c = cw[q], s = sw[q];
#pragma unroll
        for (int k0 = 0; k0 < 16; ++k0) {
            if (k0 & (1 << q)) continue;
            const int k1 = k0 | (1 << q);
            const float ar = yr[k0], ai = yi[k0];
            const float br = yr[k1], bi = yi[k1];
            yr[k0] = fmaf(c, ar,  s * bi);
            yi[k0] = fmaf(c, ai, -(s * br));
            yr[k1] = fmaf(c, br,  s * ai);
            yi[k1] = fmaf(c, bi, -(s * ar));
        }
    }

    float o0 = 0.f, o1 = 0.f, o2 = 0.f, o3 = 0.f;
#pragma unroll
    for (int j = 0; j < 16; ++j) {
        const float p = fmaf(yr[j], yr[j], yi[j] * yi[j]);
        const int q0 = j & 1, q1 = (j >> 1) & 1, q2 = (j >> 2) & 1, q3 = (j >> 3) & 1;
        if (q0 ^ q1 ^ q2 ^ q3) o0 += p;
        if (q0 ^ q1 ^ q2)      o1 += p;
        if (q0 ^ q1)           o2 += p;
        if (q1 ^ q2 ^ q3)      o3 += p;
    }
    res->x = 0.0625f * o0;
    res->y = 0.0625f * o1;
    res->z = 0.0625f * o2;
    res->w = 0.0625f * o3;
}

__global__ __launch_bounds__(256) void qconv2d_kernel(
    const float* __restrict__ x,   // [64, 256, 256]
    const float* __restrict__ w,   // [4]
    float* __restrict__ out)       // [64, 128, 128, 4]
{
    const int t = blockIdx.x * 256 + threadIdx.x;   // 2 patches per thread
    const int uh = t & 63;              // u-pair index: patches 2*uh, 2*uh+1
    const int v  = (t >> 6) & 127;
    const int b  = t >> 13;

    // rows 2v, 2v+1; cols 4*uh .. 4*uh+3
    const float* base = x + ((size_t)b << 16) + ((size_t)(v << 1) << 8) + (uh << 2);
    const float4 r0 = *(const float4*)(base);
    const float4 r1 = *(const float4*)(base + 256);

    float cw[4], sw[4];
#pragma unroll
    for (int q = 0; q < 4; ++q) {
        const float r = w[q] * (0.5f * INV2PI);
        sw[q] = __builtin_amdgcn_sinf(r);
        cw[q] = __builtin_amdgcn_cosf(r);
    }

    float4 resA, resB;
    patch_eval(r0.x, r0.y, r1.x, r1.y, cw, sw, &resA);   // patch u = 2*uh
    patch_eval(r0.z, r0.w, r1.z, r1.w, cw, sw, &resB);   // patch u = 2*uh+1

    // out[b, v, u, 0..3]; u = 2*uh and 2*uh+1 -> 32B contiguous
    float4* o = (float4*)(out + (((size_t)t) << 3));
    o[0] = resA;
    o[1] = resB;
}

extern "C" void kernel_launch(void* const* d_in, const int* in_sizes, int n_in,
                              void* d_out, int out_size, void* d_ws, size_t ws_size,
                              hipStream_t stream) {
    const float* x = (const float*)d_in[0];   // [64,256,256] fp32
    const float* w = (const float*)d_in[1];   // [2,2] fp32
    float* out = (float*)d_out;               // [64,128,128,4] fp32

    const int total = 64 * 128 * 64;          // two patches per thread
    qconv2d_kernel<<<dim3(total / 256), dim3(256), 0, stream>>>(x, w, out);
}